// Round 1
// baseline (841.782 us; speedup 1.0000x reference)
//
#include <hip/hip_runtime.h>
#include <math.h>

#define N 1024
#define C 384
#define H 12
#define CH 32
#define DP 128
#define HP 144
#define SCALING 0.17677669529663687f
#define LN_EPS 1e-5f

// ---------------- K1: fused projections GEMM ----------------
// [1024,384] @ concat(Wq|Wk|Wv|Wpq|Wpk) + bias. BN=48 aligns with all matrix
// boundaries (384/48=8, 144/48=3) so each block touches exactly one matrix.
__global__ __launch_bounds__(256) void k_qkv(
    const float* __restrict__ single,
    const float* __restrict__ Wq, const float* __restrict__ bq,
    const float* __restrict__ Wk, const float* __restrict__ bk,
    const float* __restrict__ Wv, const float* __restrict__ bv,
    const float* __restrict__ Wpq, const float* __restrict__ bpq,
    const float* __restrict__ Wpk, const float* __restrict__ bpk,
    float* __restrict__ q, float* __restrict__ kT, float* __restrict__ v,
    float* __restrict__ qp, float* __restrict__ kp)
{
  __shared__ __align__(16) float A_s[64 * 33];   // pad 33 -> 2-way max conflict
  __shared__ __align__(16) float B_s[32 * 48];
  int t = threadIdx.x;
  int nt = blockIdx.x, mt = blockIdx.y;
  int m0 = mt * 64;
  const float* W; const float* bias; int ld, kind, cb;
  if (nt < 8)       { W = Wq;  bias = bq;  ld = C;  cb = nt * 48;        kind = 0; }
  else if (nt < 16) { W = Wk;  bias = bk;  ld = C;  cb = (nt - 8) * 48;  kind = 1; }
  else if (nt < 24) { W = Wv;  bias = bv;  ld = C;  cb = (nt - 16) * 48; kind = 2; }
  else if (nt < 27) { W = Wpq; bias = bpq; ld = HP; cb = (nt - 24) * 48; kind = 3; }
  else              { W = Wpk; bias = bpk; ld = HP; cb = (nt - 27) * 48; kind = 4; }
  int tr = t >> 4, tc = t & 15;
  float acc[4][3] = {};
  for (int k0 = 0; k0 < C; k0 += 32) {
    if (k0) __syncthreads();
    #pragma unroll
    for (int i = 0; i < 8; i++) {        // A: 64x32
      int fi = i * 256 + t; int row = fi >> 5, col = fi & 31;
      A_s[row * 33 + col] = single[(m0 + row) * C + k0 + col];
    }
    #pragma unroll
    for (int i = 0; i < 6; i++) {        // B: 32x48
      int fi = i * 256 + t; int row = fi / 48, col = fi % 48;
      B_s[row * 48 + col] = W[(k0 + row) * ld + cb + col];
    }
    __syncthreads();
    #pragma unroll
    for (int k = 0; k < 32; k++) {
      float a[4], b[3];
      #pragma unroll
      for (int r = 0; r < 4; r++) a[r] = A_s[(tr * 4 + r) * 33 + k];
      #pragma unroll
      for (int c = 0; c < 3; c++) b[c] = B_s[k * 48 + tc * 3 + c];
      #pragma unroll
      for (int r = 0; r < 4; r++)
        #pragma unroll
        for (int c = 0; c < 3; c++) acc[r][c] = fmaf(a[r], b[c], acc[r][c]);
    }
  }
  #pragma unroll
  for (int c = 0; c < 3; c++) {
    int col = cb + tc * 3 + c;
    float bb = bias[col];
    #pragma unroll
    for (int r = 0; r < 4; r++) {
      int row = m0 + tr * 4 + r;
      float val = acc[r][c] + bb;
      if (kind == 0)      q[row * C + col] = val;
      else if (kind == 1) kT[col * N + row] = val;     // transposed for k_attn
      else if (kind == 2) v[row * C + col] = val;
      else if (kind == 3) qp[row * HP + col] = val;
      else                kp[row * HP + col] = val;
    }
  }
}

// ---------------- K1b: rotate points, sq/sk sums ----------------
__global__ __launch_bounds__(256) void k_rot(
    const float* __restrict__ qp, const float* __restrict__ kp,
    const float* __restrict__ rot,
    float* __restrict__ qg, float* __restrict__ kgT,
    float* __restrict__ sq, float* __restrict__ skT)
{
  __shared__ __align__(16) float qp_s[HP], kp_s[HP], rot_s[9], q2_s[HP], k2_s[HP];
  int n = blockIdx.x, t = threadIdx.x;
  if (t < HP) { qp_s[t] = qp[n * HP + t]; kp_s[t] = kp[n * HP + t]; }
  if (t < 9)  rot_s[t] = rot[n * 9 + t];
  __syncthreads();
  if (t < HP) {
    int h = t / 12, r12 = t % 12, y = r12 >> 2, p = r12 & 3;
    float qgv = rot_s[y*3] * qp_s[h*12 + p] + rot_s[y*3+1] * qp_s[h*12 + 4 + p]
              + rot_s[y*3+2] * qp_s[h*12 + 8 + p];
    float kgv = rot_s[y*3] * kp_s[h*12 + p] + rot_s[y*3+1] * kp_s[h*12 + 4 + p]
              + rot_s[y*3+2] * kp_s[h*12 + 8 + p];
    qg[n * HP + t] = qgv; kgT[t * N + n] = kgv;
    q2_s[t] = qgv * qgv; k2_s[t] = kgv * kgv;
  }
  __syncthreads();
  if (t < H) {
    float s1 = 0.f, s2 = 0.f;
    #pragma unroll
    for (int e = 0; e < 12; e++) { s1 += q2_s[t * 12 + e]; s2 += k2_s[t * 12 + e]; }
    sq[n * H + t] = s1; skT[t * N + n] = s2;
  }
}

// ---------------- K2: pair bias GEMM [N*N,128] @ [128,12] ----------------
// The HBM-dominant kernel: streams 512 MB of pair. XOR-swizzled float4 LDS
// tile (conflict-free b128 both sides); Wp via LDS broadcast (free);
// pb stored [H][N*N] -> coalesced stores and coalesced reads in k_attn.
__global__ __launch_bounds__(256) void k_pb(
    const float4* __restrict__ pair4, const float* __restrict__ Wp,
    const float* __restrict__ bp, float* __restrict__ pb)
{
  __shared__ __align__(16) float4 pair_s[256 * 8];  // 32 KB, swizzled
  __shared__ __align__(16) float wp_s[12 * 128];    // Wp transposed [h][d]
  int t = threadIdx.x;
  long r0 = (long)blockIdx.x * 256;
  #pragma unroll
  for (int i = 0; i < 6; i++) {
    int fi = i * 256 + t; int h = fi >> 7, d = fi & 127;
    wp_s[h * 128 + d] = Wp[d * 12 + h];
  }
  float acc[12] = {};
  const float4* wp4 = (const float4*)wp_s;
  for (int chunk = 0; chunk < 4; chunk++) {
    if (chunk) __syncthreads();
    #pragma unroll
    for (int i = 0; i < 8; i++) {
      int fi = i * 256 + t; int row = fi >> 3, q4 = fi & 7;
      pair_s[row * 8 + (q4 ^ (row & 7))] = pair4[(r0 + row) * 32 + chunk * 8 + q4];
    }
    __syncthreads();
    #pragma unroll
    for (int d4 = 0; d4 < 8; d4++) {
      float4 a = pair_s[t * 8 + (d4 ^ (t & 7))];
      #pragma unroll
      for (int h = 0; h < 12; h++) {
        float4 w = wp4[h * 32 + chunk * 8 + d4];
        acc[h] = fmaf(a.x, w.x, acc[h]);
        acc[h] = fmaf(a.y, w.y, acc[h]);
        acc[h] = fmaf(a.z, w.z, acc[h]);
        acc[h] = fmaf(a.w, w.w, acc[h]);
      }
    }
  }
  #pragma unroll
  for (int h = 0; h < 12; h++)
    pb[(long)h * (N * (long)N) + r0 + t] = acc[h] + bp[h];
}

// ---------------- K3: flash attention ----------------
// 4 query rows per block; 12 waves = 12 heads; lanes = 64 keys per tile.
__global__ __launch_bounds__(768) void k_attn(
    const float* __restrict__ q, const float* __restrict__ kT,
    const float* __restrict__ v, const float* __restrict__ qg,
    const float* __restrict__ kgT, const float* __restrict__ sq,
    const float* __restrict__ skT, const float* __restrict__ pb,
    float* __restrict__ wt)
{
  __shared__ __align__(16) float q_s[4 * C];
  __shared__ __align__(16) float qg_s[4 * HP];
  __shared__ __align__(16) float sq_s[4 * H];
  __shared__ __align__(16) float p_s[4 * 768];
  __shared__ __align__(16) float scale_s[4 * H];
  int t = threadIdx.x;
  int n0 = blockIdx.x * 4;
  int h = t >> 6, lane = t & 63;
  for (int idx = t; idx < 4 * C; idx += 768) q_s[idx] = q[n0 * C + idx];
  for (int idx = t; idx < 4 * HP; idx += 768) qg_s[idx] = qg[n0 * HP + idx];
  if (t < 4 * H) sq_s[t] = sq[n0 * H + t];
  __syncthreads();
  float mrun[4], lrun[4] = {}, o[4] = {};
  #pragma unroll
  for (int i = 0; i < 4; i++) mrun[i] = -INFINITY;
  for (int tile = 0; tile < 16; tile++) {
    int m0 = tile * 64, m = m0 + lane;
    float Lq[4] = {}, Lp[4] = {};
    #pragma unroll
    for (int c = 0; c < 32; c++) {
      float kc = kT[(h * 32 + c) * N + m];
      #pragma unroll
      for (int i = 0; i < 4; i++) Lq[i] = fmaf(q_s[i * C + h * 32 + c], kc, Lq[i]);
    }
    #pragma unroll
    for (int e = 0; e < 12; e++) {
      float ke = kgT[(h * 12 + e) * N + m];
      #pragma unroll
      for (int i = 0; i < 4; i++) Lp[i] = fmaf(qg_s[i * HP + h * 12 + e], ke, Lp[i]);
    }
    float skm = skT[h * N + m];
    float L[4];
    #pragma unroll
    for (int i = 0; i < 4; i++) {
      float pbv = pb[(long)h * (N * (long)N) + (long)(n0 + i) * N + m];
      L[i] = Lq[i] * SCALING + pbv
           - 0.5f * SCALING * (sq_s[i * H + h] + skm - 2.0f * Lp[i]);
    }
    #pragma unroll
    for (int i = 0; i < 4; i++) {
      float tmax = L[i];
      #pragma unroll
      for (int off = 32; off; off >>= 1) tmax = fmaxf(tmax, __shfl_xor(tmax, off));
      float mnew = fmaxf(mrun[i], tmax);
      float p = __expf(L[i] - mnew);
      float ts = p;
      #pragma unroll
      for (int off = 32; off; off >>= 1) ts += __shfl_xor(ts, off);
      float sc = __expf(mrun[i] - mnew);   // first tile: exp(-inf)=0, lrun=0 anyway
      lrun[i] = lrun[i] * sc + ts;
      mrun[i] = mnew;
      p_s[i * 768 + t] = p;
      if (lane == 0) scale_s[i * H + h] = sc;
    }
    __syncthreads();
    {
      int c = lane & 31, seg = lane >> 5;
      float vr[32];
      #pragma unroll
      for (int jj = 0; jj < 32; jj++)
        vr[jj] = v[(m0 + seg * 32 + jj) * C + h * 32 + c];
      #pragma unroll
      for (int i = 0; i < 4; i++) {
        float accv = o[i] * scale_s[i * H + h];
        const float4* p4 = (const float4*)&p_s[i * 768 + h * 64 + seg * 32];
        #pragma unroll
        for (int j4 = 0; j4 < 8; j4++) {
          float4 pv = p4[j4];
          accv = fmaf(pv.x, vr[j4 * 4],     accv);
          accv = fmaf(pv.y, vr[j4 * 4 + 1], accv);
          accv = fmaf(pv.z, vr[j4 * 4 + 2], accv);
          accv = fmaf(pv.w, vr[j4 * 4 + 3], accv);
        }
        o[i] = accv;
      }
    }
    __syncthreads();
  }
  #pragma unroll
  for (int i = 0; i < 4; i++) {
    float ov = o[i] + __shfl_xor(o[i], 32);   // combine the two key-halves
    if (lane < 32) wt[(n0 + i) * C + h * 32 + lane] = ov / lrun[i];
  }
}

// ---------------- K4: output GEMM + residual + LayerNorm ----------------
__global__ __launch_bounds__(384) void k_out(
    const float* __restrict__ wt, const float* __restrict__ Wo,
    const float* __restrict__ bo, const float* __restrict__ single,
    const float* __restrict__ gamma, const float* __restrict__ beta,
    float* __restrict__ out)
{
  __shared__ __align__(16) float wt_s[4 * C];
  __shared__ __align__(16) float red[4][2][6];
  int t = threadIdx.x, n0 = blockIdx.x * 4;
  for (int idx = t; idx < 4 * C; idx += 384) wt_s[idx] = wt[n0 * C + idx];
  __syncthreads();
  float acc[4] = {};
  for (int ck = 0; ck < C; ck++) {
    float w = Wo[ck * C + t];
    #pragma unroll
    for (int i = 0; i < 4; i++) acc[i] = fmaf(wt_s[i * C + ck], w, acc[i]);
  }
  float x[4], bov = bo[t];
  #pragma unroll
  for (int i = 0; i < 4; i++) x[i] = single[(n0 + i) * C + t] + acc[i] + bov;
  int wid = t >> 6, lane = t & 63;
  #pragma unroll
  for (int i = 0; i < 4; i++) {
    float s = x[i], s2 = x[i] * x[i];
    #pragma unroll
    for (int off = 32; off; off >>= 1) { s += __shfl_xor(s, off); s2 += __shfl_xor(s2, off); }
    if (lane == 0) { red[i][0][wid] = s; red[i][1][wid] = s2; }
  }
  __syncthreads();
  float gv = gamma[t], bv = beta[t];
  #pragma unroll
  for (int i = 0; i < 4; i++) {
    float S = 0.f, S2 = 0.f;
    #pragma unroll
    for (int w = 0; w < 6; w++) { S += red[i][0][w]; S2 += red[i][1][w]; }
    float mu = S * (1.0f / C);
    float var = S2 * (1.0f / C) - mu * mu;
    out[(n0 + i) * C + t] = (x[i] - mu) * rsqrtf(var + LN_EPS) * gv + bv;
  }
}

extern "C" void kernel_launch(void* const* d_in, const int* in_sizes, int n_in,
                              void* d_out, int out_size, void* d_ws, size_t ws_size,
                              hipStream_t stream) {
  const float* single = (const float*)d_in[0];
  const float* pair   = (const float*)d_in[1];
  const float* rot    = (const float*)d_in[2];
  // d_in[3] translations: unused by the reference
  const float* Wq  = (const float*)d_in[4];  const float* bq  = (const float*)d_in[5];
  const float* Wk  = (const float*)d_in[6];  const float* bk  = (const float*)d_in[7];
  const float* Wv  = (const float*)d_in[8];  const float* bv  = (const float*)d_in[9];
  const float* Wp  = (const float*)d_in[10]; const float* bp  = (const float*)d_in[11];
  const float* Wpq = (const float*)d_in[12]; const float* bpq = (const float*)d_in[13];
  const float* Wpk = (const float*)d_in[14]; const float* bpk = (const float*)d_in[15];
  const float* Wo  = (const float*)d_in[16]; const float* bo  = (const float*)d_in[17];
  const float* gamma = (const float*)d_in[18]; const float* beta = (const float*)d_in[19];

  float* ws  = (float*)d_ws;                 // needs ~59 MB of workspace
  float* pb  = ws;                           // [12][1024*1024]
  float* q   = pb + 12L * N * N;             // [N][C]
  float* kT  = q   + N * C;                  // [C][N]
  float* v   = kT  + N * C;                  // [N][C]
  float* qp  = v   + N * C;                  // [N][144]
  float* kp  = qp  + N * HP;                 // [N][144]
  float* qg  = kp  + N * HP;                 // [N][144]
  float* kgT = qg  + N * HP;                 // [144][N]
  float* sq  = kgT + N * HP;                 // [N][12]
  float* skT = sq  + N * H;                  // [12][N]
  float* wt  = skT + N * H;                  // [N][C]

  k_qkv<<<dim3(30, 16), 256, 0, stream>>>(single, Wq, bq, Wk, bk, Wv, bv,
                                          Wpq, bpq, Wpk, bpk, q, kT, v, qp, kp);
  k_rot<<<N, 256, 0, stream>>>(qp, kp, rot, qg, kgT, sq, skT);
  k_pb<<<4096, 256, 0, stream>>>((const float4*)pair, Wp, bp, pb);
  k_attn<<<256, 768, 0, stream>>>(q, kT, v, qg, kgT, sq, skT, pb, wt);
  k_out<<<256, 384, 0, stream>>>(wt, Wo, bo, single, gamma, beta, (float*)d_out);
}

// Round 2
// 548.752 us; speedup vs baseline: 1.5340x; 1.5340x over previous
//
#include <hip/hip_runtime.h>
#include <math.h>

#define N 1024
#define C 384
#define H 12
#define CH 32
#define DP 128
#define HP 144
#define QB 16
#define SCALING 0.17677669529663687f
#define LN_EPS 1e-5f

// ---------------- K1: fused projections GEMM ----------------
// [1024,384] @ concat(Wq|Wk|Wv|Wpq|Wpk) + bias. BN=48 aligns with all matrix
// boundaries (384/48=8, 144/48=3) so each block touches exactly one matrix.
__global__ __launch_bounds__(256) void k_qkv(
    const float* __restrict__ single,
    const float* __restrict__ Wq, const float* __restrict__ bq,
    const float* __restrict__ Wk, const float* __restrict__ bk,
    const float* __restrict__ Wv, const float* __restrict__ bv,
    const float* __restrict__ Wpq, const float* __restrict__ bpq,
    const float* __restrict__ Wpk, const float* __restrict__ bpk,
    float* __restrict__ q, float* __restrict__ kT, float* __restrict__ v,
    float* __restrict__ qp, float* __restrict__ kp)
{
  __shared__ __align__(16) float A_s[64 * 33];
  __shared__ __align__(16) float B_s[32 * 48];
  int t = threadIdx.x;
  int nt = blockIdx.x, mt = blockIdx.y;
  int m0 = mt * 64;
  const float* W; const float* bias; int ld, kind, cb;
  if (nt < 8)       { W = Wq;  bias = bq;  ld = C;  cb = nt * 48;        kind = 0; }
  else if (nt < 16) { W = Wk;  bias = bk;  ld = C;  cb = (nt - 8) * 48;  kind = 1; }
  else if (nt < 24) { W = Wv;  bias = bv;  ld = C;  cb = (nt - 16) * 48; kind = 2; }
  else if (nt < 27) { W = Wpq; bias = bpq; ld = HP; cb = (nt - 24) * 48; kind = 3; }
  else              { W = Wpk; bias = bpk; ld = HP; cb = (nt - 27) * 48; kind = 4; }
  int tr = t >> 4, tc = t & 15;
  float acc[4][3] = {};
  for (int k0 = 0; k0 < C; k0 += 32) {
    if (k0) __syncthreads();
    #pragma unroll
    for (int i = 0; i < 8; i++) {
      int fi = i * 256 + t; int row = fi >> 5, col = fi & 31;
      A_s[row * 33 + col] = single[(m0 + row) * C + k0 + col];
    }
    #pragma unroll
    for (int i = 0; i < 6; i++) {
      int fi = i * 256 + t; int row = fi / 48, col = fi % 48;
      B_s[row * 48 + col] = W[(k0 + row) * ld + cb + col];
    }
    __syncthreads();
    #pragma unroll
    for (int k = 0; k < 32; k++) {
      float a[4], b[3];
      #pragma unroll
      for (int r = 0; r < 4; r++) a[r] = A_s[(tr * 4 + r) * 33 + k];
      #pragma unroll
      for (int c = 0; c < 3; c++) b[c] = B_s[k * 48 + tc * 3 + c];
      #pragma unroll
      for (int r = 0; r < 4; r++)
        #pragma unroll
        for (int c = 0; c < 3; c++) acc[r][c] = fmaf(a[r], b[c], acc[r][c]);
    }
  }
  #pragma unroll
  for (int c = 0; c < 3; c++) {
    int col = cb + tc * 3 + c;
    float bb = bias[col];
    #pragma unroll
    for (int r = 0; r < 4; r++) {
      int row = m0 + tr * 4 + r;
      float val = acc[r][c] + bb;
      if (kind == 0)      q[row * C + col] = val;
      else if (kind == 1) kT[col * N + row] = val;
      else if (kind == 2) v[row * C + col] = val;
      else if (kind == 3) qp[row * HP + col] = val;
      else                kp[row * HP + col] = val;
    }
  }
}

// ---------------- K1b: rotate points, sq/sk sums ----------------
__global__ __launch_bounds__(256) void k_rot(
    const float* __restrict__ qp, const float* __restrict__ kp,
    const float* __restrict__ rot,
    float* __restrict__ qg, float* __restrict__ kgT,
    float* __restrict__ sq, float* __restrict__ skT)
{
  __shared__ __align__(16) float qp_s[HP], kp_s[HP], rot_s[9], q2_s[HP], k2_s[HP];
  int n = blockIdx.x, t = threadIdx.x;
  if (t < HP) { qp_s[t] = qp[n * HP + t]; kp_s[t] = kp[n * HP + t]; }
  if (t < 9)  rot_s[t] = rot[n * 9 + t];
  __syncthreads();
  if (t < HP) {
    int h = t / 12, r12 = t % 12, y = r12 >> 2, p = r12 & 3;
    float qgv = rot_s[y*3] * qp_s[h*12 + p] + rot_s[y*3+1] * qp_s[h*12 + 4 + p]
              + rot_s[y*3+2] * qp_s[h*12 + 8 + p];
    float kgv = rot_s[y*3] * kp_s[h*12 + p] + rot_s[y*3+1] * kp_s[h*12 + 4 + p]
              + rot_s[y*3+2] * kp_s[h*12 + 8 + p];
    qg[n * HP + t] = qgv; kgT[t * N + n] = kgv;
    q2_s[t] = qgv * qgv; k2_s[t] = kgv * kgv;
  }
  __syncthreads();
  if (t < H) {
    float s1 = 0.f, s2 = 0.f;
    #pragma unroll
    for (int e = 0; e < 12; e++) { s1 += q2_s[t * 12 + e]; s2 += k2_s[t * 12 + e]; }
    sq[n * H + t] = s1; skT[t * N + n] = s2;
  }
}

// ---------------- K2: pair bias GEMM [N*N,128] @ [128,12] ----------------
__global__ __launch_bounds__(256) void k_pb(
    const float4* __restrict__ pair4, const float* __restrict__ Wp,
    const float* __restrict__ bp, float* __restrict__ pb)
{
  __shared__ __align__(16) float4 pair_s[256 * 8];
  __shared__ __align__(16) float wp_s[12 * 128];
  int t = threadIdx.x;
  long r0 = (long)blockIdx.x * 256;
  #pragma unroll
  for (int i = 0; i < 6; i++) {
    int fi = i * 256 + t; int h = fi >> 7, d = fi & 127;
    wp_s[h * 128 + d] = Wp[d * 12 + h];
  }
  float acc[12] = {};
  const float4* wp4 = (const float4*)wp_s;
  for (int chunk = 0; chunk < 4; chunk++) {
    if (chunk) __syncthreads();
    #pragma unroll
    for (int i = 0; i < 8; i++) {
      int fi = i * 256 + t; int row = fi >> 3, q4 = fi & 7;
      pair_s[row * 8 + (q4 ^ (row & 7))] = pair4[(r0 + row) * 32 + chunk * 8 + q4];
    }
    __syncthreads();
    #pragma unroll
    for (int d4 = 0; d4 < 8; d4++) {
      float4 a = pair_s[t * 8 + (d4 ^ (t & 7))];
      #pragma unroll
      for (int h = 0; h < 12; h++) {
        float4 w = wp4[h * 32 + chunk * 8 + d4];
        acc[h] = fmaf(a.x, w.x, acc[h]);
        acc[h] = fmaf(a.y, w.y, acc[h]);
        acc[h] = fmaf(a.z, w.z, acc[h]);
        acc[h] = fmaf(a.w, w.w, acc[h]);
      }
    }
  }
  #pragma unroll
  for (int h = 0; h < 12; h++)
    pb[(long)h * (N * (long)N) + r0 + t] = acc[h] + bp[h];
}

// ---------------- K3: flash attention, one head per block ----------------
// Grid (64 query-blocks x 12 heads), 256 threads = 4 waves x 4 rows.
// Each block touches only its head slice (~370 KB) -> total k/v/kg re-read
// ~100 MB (was 940 MB). No __syncthreads in the tile loop: k/v/pb come
// straight from global (L1/L2-cached), p_s rows are private to each wave.
__global__ __launch_bounds__(256) void k_attn(
    const float* __restrict__ q, const float* __restrict__ kT,
    const float* __restrict__ v, const float* __restrict__ qg,
    const float* __restrict__ kgT, const float* __restrict__ sq,
    const float* __restrict__ skT, const float* __restrict__ pb,
    float* __restrict__ wt)
{
  __shared__ float q_s[QB][32];
  __shared__ float qg_s[QB][12];
  __shared__ float sq_s[QB];
  __shared__ __align__(16) float p_s[QB][64];
  int t = threadIdx.x;
  int nb = blockIdx.x, h = blockIdx.y;
  int n0 = nb * QB;
  int w = t >> 6, lane = t & 63;
  for (int idx = t; idx < QB * 32; idx += 256) {
    int i = idx >> 5, c = idx & 31;
    q_s[i][c] = q[(n0 + i) * C + h * 32 + c];
  }
  for (int idx = t; idx < QB * 12; idx += 256) {
    int i = idx / 12, e = idx % 12;
    qg_s[i][e] = qg[(n0 + i) * HP + h * 12 + e];
  }
  if (t < QB) sq_s[t] = sq[(n0 + t) * H + h];
  __syncthreads();
  float mrun[4], lrun[4] = {}, o[4] = {};
  #pragma unroll
  for (int i = 0; i < 4; i++) mrun[i] = -INFINITY;
  int r0 = w * 4;
  for (int tile = 0; tile < 16; tile++) {
    int m0 = tile * 64, m = m0 + lane;
    float Lq[4] = {}, Lp[4] = {};
    #pragma unroll
    for (int c = 0; c < 32; c++) {
      float kc = kT[(h * 32 + c) * N + m];
      #pragma unroll
      for (int i = 0; i < 4; i++) Lq[i] = fmaf(q_s[r0 + i][c], kc, Lq[i]);
    }
    #pragma unroll
    for (int e = 0; e < 12; e++) {
      float ke = kgT[(h * 12 + e) * N + m];
      #pragma unroll
      for (int i = 0; i < 4; i++) Lp[i] = fmaf(qg_s[r0 + i][e], ke, Lp[i]);
    }
    float skm = skT[h * N + m];
    float L[4];
    #pragma unroll
    for (int i = 0; i < 4; i++) {
      float pbv = pb[(long)h * (N * (long)N) + (long)(n0 + r0 + i) * N + m];
      L[i] = Lq[i] * SCALING + pbv
           - 0.5f * SCALING * (sq_s[r0 + i] + skm - 2.0f * Lp[i]);
    }
    float sc[4];
    #pragma unroll
    for (int i = 0; i < 4; i++) {
      float tmax = L[i];
      #pragma unroll
      for (int off = 32; off; off >>= 1) tmax = fmaxf(tmax, __shfl_xor(tmax, off));
      float mnew = fmaxf(mrun[i], tmax);
      float p = __expf(L[i] - mnew);
      float ts = p;
      #pragma unroll
      for (int off = 32; off; off >>= 1) ts += __shfl_xor(ts, off);
      sc[i] = __expf(mrun[i] - mnew);
      lrun[i] = lrun[i] * sc[i] + ts;
      mrun[i] = mnew;
      p_s[r0 + i][lane] = p;   // wave-private rows: same wave reads below
    }
    {
      int c = lane & 31, seg = lane >> 5;
      float vr[32];
      #pragma unroll
      for (int jj = 0; jj < 32; jj++)
        vr[jj] = v[(m0 + seg * 32 + jj) * C + h * 32 + c];
      #pragma unroll
      for (int i = 0; i < 4; i++) {
        float accv = o[i] * sc[i];
        const float4* p4 = (const float4*)&p_s[r0 + i][seg * 32];
        #pragma unroll
        for (int j4 = 0; j4 < 8; j4++) {
          float4 pv = p4[j4];
          accv = fmaf(pv.x, vr[j4 * 4],     accv);
          accv = fmaf(pv.y, vr[j4 * 4 + 1], accv);
          accv = fmaf(pv.z, vr[j4 * 4 + 2], accv);
          accv = fmaf(pv.w, vr[j4 * 4 + 3], accv);
        }
        o[i] = accv;
      }
    }
  }
  #pragma unroll
  for (int i = 0; i < 4; i++) {
    float ov = o[i] + __shfl_xor(o[i], 32);
    if (lane < 32) wt[(n0 + r0 + i) * C + h * 32 + lane] = ov / lrun[i];
  }
}

// ---------------- K4: output GEMM + residual + LayerNorm ----------------
__global__ __launch_bounds__(384) void k_out(
    const float* __restrict__ wt, const float* __restrict__ Wo,
    const float* __restrict__ bo, const float* __restrict__ single,
    const float* __restrict__ gamma, const float* __restrict__ beta,
    float* __restrict__ out)
{
  __shared__ __align__(16) float wt_s[4 * C];
  __shared__ __align__(16) float red[4][2][6];
  int t = threadIdx.x, n0 = blockIdx.x * 4;
  for (int idx = t; idx < 4 * C; idx += 384) wt_s[idx] = wt[n0 * C + idx];
  __syncthreads();
  float acc[4] = {};
  for (int ck = 0; ck < C; ck++) {
    float w = Wo[ck * C + t];
    #pragma unroll
    for (int i = 0; i < 4; i++) acc[i] = fmaf(wt_s[i * C + ck], w, acc[i]);
  }
  float x[4], bov = bo[t];
  #pragma unroll
  for (int i = 0; i < 4; i++) x[i] = single[(n0 + i) * C + t] + acc[i] + bov;
  int wid = t >> 6, lane = t & 63;
  #pragma unroll
  for (int i = 0; i < 4; i++) {
    float s = x[i], s2 = x[i] * x[i];
    #pragma unroll
    for (int off = 32; off; off >>= 1) { s += __shfl_xor(s, off); s2 += __shfl_xor(s2, off); }
    if (lane == 0) { red[i][0][wid] = s; red[i][1][wid] = s2; }
  }
  __syncthreads();
  float gv = gamma[t], bv = beta[t];
  #pragma unroll
  for (int i = 0; i < 4; i++) {
    float S = 0.f, S2 = 0.f;
    #pragma unroll
    for (int w = 0; w < 6; w++) { S += red[i][0][w]; S2 += red[i][1][w]; }
    float mu = S * (1.0f / C);
    float var = S2 * (1.0f / C) - mu * mu;
    out[(n0 + i) * C + t] = (x[i] - mu) * rsqrtf(var + LN_EPS) * gv + bv;
  }
}

extern "C" void kernel_launch(void* const* d_in, const int* in_sizes, int n_in,
                              void* d_out, int out_size, void* d_ws, size_t ws_size,
                              hipStream_t stream) {
  const float* single = (const float*)d_in[0];
  const float* pair   = (const float*)d_in[1];
  const float* rot    = (const float*)d_in[2];
  const float* Wq  = (const float*)d_in[4];  const float* bq  = (const float*)d_in[5];
  const float* Wk  = (const float*)d_in[6];  const float* bk  = (const float*)d_in[7];
  const float* Wv  = (const float*)d_in[8];  const float* bv  = (const float*)d_in[9];
  const float* Wp  = (const float*)d_in[10]; const float* bp  = (const float*)d_in[11];
  const float* Wpq = (const float*)d_in[12]; const float* bpq = (const float*)d_in[13];
  const float* Wpk = (const float*)d_in[14]; const float* bpk = (const float*)d_in[15];
  const float* Wo  = (const float*)d_in[16]; const float* bo  = (const float*)d_in[17];
  const float* gamma = (const float*)d_in[18]; const float* beta = (const float*)d_in[19];

  float* ws  = (float*)d_ws;
  float* pb  = ws;                           // [12][1024*1024]
  float* q   = pb + 12L * N * N;             // [N][C]
  float* kT  = q   + N * C;                  // [C][N]
  float* v   = kT  + N * C;                  // [N][C]
  float* qp  = v   + N * C;                  // [N][144]
  float* kp  = qp  + N * HP;                 // [N][144]
  float* qg  = kp  + N * HP;                 // [N][144]
  float* kgT = qg  + N * HP;                 // [144][N]
  float* sq  = kgT + N * HP;                 // [N][12]
  float* skT = sq  + N * H;                  // [12][N]
  float* wt  = skT + N * H;                  // [N][C]

  k_qkv<<<dim3(30, 16), 256, 0, stream>>>(single, Wq, bq, Wk, bk, Wv, bv,
                                          Wpq, bpq, Wpk, bpk, q, kT, v, qp, kp);
  k_rot<<<N, 256, 0, stream>>>(qp, kp, rot, qg, kgT, sq, skT);
  k_pb<<<4096, 256, 0, stream>>>((const float4*)pair, Wp, bp, pb);
  k_attn<<<dim3(64, 12), 256, 0, stream>>>(q, kT, v, qg, kgT, sq, skT, pb, wt);
  k_out<<<256, 384, 0, stream>>>(wt, Wo, bo, single, gamma, beta, (float*)d_out);
}